// Round 4
// baseline (438.299 us; speedup 1.0000x reference)
//
#include <hip/hip_runtime.h>

#define NTOK 262144   // 64*64*64 tokens per batch
#define NCH  64
#define NB   4

// ws layout (floats): S[4][4] @0, m[4][4][64] @16, rc[4][64] @1040
#define WS_S  0
#define WS_M  16
#define WS_RC 1040

__device__ __forceinline__ unsigned short f2bf(float f) {
    unsigned u = __float_as_uint(f);
    u += 0x7fffu + ((u >> 16) & 1u);     // round-to-nearest-even (values are +normal)
    return (unsigned short)(u >> 16);
}
__device__ __forceinline__ float bf2f(unsigned short s) {
    return __uint_as_float(((unsigned)s) << 16);
}

// ---------- P1: keys -> e16 (bf16) + S.  Pure row-streaming, thread = 4 tokens ----------
__global__ __launch_bounds__(256)
void ea3d_keys(const float* __restrict__ x, const float* __restrict__ Wk,
               unsigned short* __restrict__ e16, float* __restrict__ ws)
{
    __shared__ __align__(16) float wk4[NCH * 4];   // wk4[c][h]
    __shared__ float ssum[4][4];

    const int tid = threadIdx.x;
    const int w   = tid >> 6;
    const int b   = blockIdx.y;
    { int c = tid >> 2, h = tid & 3; wk4[(c << 2) + h] = Wk[h * NCH + c]; }
    __syncthreads();

    const int n0 = blockIdx.x * 1024 + tid * 4;
    const float* xb = x + (size_t)b * NCH * NTOK + n0;

    float k[16];                       // k[h*4 + j], j = token 0..3
    #pragma unroll
    for (int r = 0; r < 16; ++r) k[r] = 0.f;

    // rotate channel order per wave/block so concurrent in-flight rows spread
    // across all 64 one-MB-strided rows chip-wide (anti bank/channel camping)
    const int coff = ((blockIdx.x << 3) + (w << 4)) & 63;
    #pragma unroll 8
    for (int cc = 0; cc < NCH; ++cc) {
        const int c = (cc + coff) & 63;
        float4 xv = *(const float4*)(xb + (size_t)c * NTOK);   // 1KB/wave contiguous
        float4 wv = *((const float4*)wk4 + c);
        k[0]  += wv.x * xv.x; k[1]  += wv.x * xv.y; k[2]  += wv.x * xv.z; k[3]  += wv.x * xv.w;
        k[4]  += wv.y * xv.x; k[5]  += wv.y * xv.y; k[6]  += wv.y * xv.z; k[7]  += wv.y * xv.w;
        k[8]  += wv.z * xv.x; k[9]  += wv.z * xv.y; k[10] += wv.z * xv.z; k[11] += wv.z * xv.w;
        k[12] += wv.w * xv.x; k[13] += wv.w * xv.y; k[14] += wv.w * xv.z; k[15] += wv.w * xv.w;
    }

    float sacc[4];
    #pragma unroll
    for (int h = 0; h < 4; ++h) {
        float e0 = __expf(k[h*4+0]), e1 = __expf(k[h*4+1]),
              e2 = __expf(k[h*4+2]), e3 = __expf(k[h*4+3]);
        ushort4 u; u.x = f2bf(e0); u.y = f2bf(e1); u.z = f2bf(e2); u.w = f2bf(e3);
        *(ushort4*)(e16 + ((size_t)(b * 4 + h)) * NTOK + n0) = u;
        sacc[h] = (e0 + e1) + (e2 + e3);
    }

    #pragma unroll
    for (int h = 0; h < 4; ++h) {
        float v = sacc[h];
        #pragma unroll
        for (int off = 32; off; off >>= 1) v += __shfl_xor(v, off);
        sacc[h] = v;
    }
    if ((tid & 63) == 0) {
        #pragma unroll
        for (int h = 0; h < 4; ++h) ssum[w][h] = sacc[h];
    }
    __syncthreads();
    if (tid < 4) {
        float s = (ssum[0][tid] + ssum[1][tid]) + (ssum[2][tid] + ssum[3][tid]);
        __hip_atomic_fetch_add(ws + WS_S + b * 4 + tid, s,
                               __ATOMIC_RELAXED, __HIP_MEMORY_SCOPE_AGENT);
    }
}

// ---------- P2: m[h][c] = sum_n e[h][n] * x[c][n].  8 channels/block, streaming ----------
__global__ __launch_bounds__(256)
void ea3d_msum(const float* __restrict__ x, const unsigned short* __restrict__ e16,
               float* __restrict__ ws)
{
    const int tid = threadIdx.x;
    const int w   = tid >> 6;
    const int b   = blockIdx.z;
    const int c0  = blockIdx.y << 3;
    const size_t nb0 = (size_t)blockIdx.x * 8192 + tid * 4;
    const float* xb = x + ((size_t)b * NCH + c0) * NTOK;
    const unsigned short* eb = e16 + (size_t)b * 4 * NTOK;

    float macc[32];                    // macc[ci*4 + h]
    #pragma unroll
    for (int r = 0; r < 32; ++r) macc[r] = 0.f;

    const int coff = (blockIdx.x + w) & 7;

    for (int s = 0; s < 8; ++s) {
        const size_t n = nb0 + (size_t)s * 1024;
        float eh[16];                  // eh[h*4 + j]
        #pragma unroll
        for (int h = 0; h < 4; ++h) {
            ushort4 u = *(const ushort4*)(eb + (size_t)h * NTOK + n);
            eh[h*4+0] = bf2f(u.x); eh[h*4+1] = bf2f(u.y);
            eh[h*4+2] = bf2f(u.z); eh[h*4+3] = bf2f(u.w);
        }
        #pragma unroll
        for (int cc = 0; cc < 8; ++cc) {
            const int ci = (cc + coff) & 7;
            float4 xv = *(const float4*)(xb + (size_t)ci * NTOK + n);
            #pragma unroll
            for (int h = 0; h < 4; ++h)
                macc[ci*4+h] += eh[h*4+0]*xv.x + eh[h*4+1]*xv.y
                              + eh[h*4+2]*xv.z + eh[h*4+3]*xv.w;
        }
    }

    #pragma unroll
    for (int r = 0; r < 32; ++r) {
        float v = macc[r];
        #pragma unroll
        for (int off = 32; off; off >>= 1) v += __shfl_xor(v, off);
        macc[r] = v;
    }
    if ((tid & 63) == 0) {
        float* mb = ws + WS_M + (size_t)(b * 4) * NCH + c0;
        #pragma unroll
        for (int ci = 0; ci < 8; ++ci) {
            #pragma unroll
            for (int h = 0; h < 4; ++h)
                __hip_atomic_fetch_add(mb + h * NCH + ci, macc[ci*4+h],
                                       __ATOMIC_RELAXED, __HIP_MEMORY_SCOPE_AGENT);
        }
    }
}

// ---------- finalize: context = Wv*(m/S)+bv ; rc = Wr*context + br ----------
__global__ void ea3d_finalize(const float* __restrict__ Wv, const float* __restrict__ bv,
                              const float* __restrict__ Wr, const float* __restrict__ br,
                              float* __restrict__ ws)
{
    __shared__ float ctx[NB * 32];
    const int tid = threadIdx.x;
    if (tid < 128) {
        int b = tid >> 5, hv = tid & 31, h = hv >> 3;
        float inv = 1.0f / ws[WS_S + b * 4 + h];
        const float* m = ws + WS_M + (b * 4 + h) * NCH;
        const float* wvr = Wv + hv * NCH;
        float acc = 0.f;
        #pragma unroll
        for (int c = 0; c < NCH; ++c) acc += wvr[c] * m[c];
        ctx[b * 32 + hv] = acc * inv + bv[hv];
    }
    __syncthreads();
    int b = tid >> 6, c = tid & 63;
    const float* wrr = Wr + c * 32;
    const float* cb  = ctx + b * 32;
    float acc = br[c];
    #pragma unroll
    for (int hv = 0; hv < 32; ++hv) acc += wrr[hv] * cb[hv];
    ws[WS_RC + b * NCH + c] = acc;
}

// ---------- P3: out = x + rc[b][c] ----------
__global__ __launch_bounds__(256)
void ea3d_add(const float* __restrict__ x, const float* __restrict__ ws,
              float* __restrict__ out)
{
    const int row = blockIdx.y;                 // b*64 + c
    const float rc = ws[WS_RC + row];
    const size_t base = (size_t)row * NTOK;
    const float4* xp = (const float4*)(x + base);
    float4*       op = (float4*)(out + base);
    const int nvec = NTOK / 4;
    for (int i = blockIdx.x * blockDim.x + threadIdx.x; i < nvec;
         i += gridDim.x * blockDim.x) {
        float4 v = xp[i];
        v.x += rc; v.y += rc; v.z += rc; v.w += rc;
        op[i] = v;
    }
}

extern "C" void kernel_launch(void* const* d_in, const int* in_sizes, int n_in,
                              void* d_out, int out_size, void* d_ws, size_t ws_size,
                              hipStream_t stream)
{
    const float* x  = (const float*)d_in[0];
    const float* Wk = (const float*)d_in[1];
    // d_in[2]=bk (cancels in token-softmax); d_in[3]=Wq, d_in[4]=bq (softmax over
    // size-1 head-channel axis -> identically 1.0, so Wq/bq are dead)
    const float* Wv = (const float*)d_in[5];
    const float* bv = (const float*)d_in[6];
    const float* Wr = (const float*)d_in[7];
    const float* br = (const float*)d_in[8];
    float* out = (float*)d_out;
    float* ws  = (float*)d_ws;

    // e16 scratch (8 MB, bf16 e[b][h][n]) lives in the head of d_out:
    // written by P1, read by P2, fully overwritten by P3 afterwards.
    unsigned short* e16 = (unsigned short*)d_out;

    hipMemsetAsync(ws, 0, WS_RC * sizeof(float), stream);   // zero S + m accumulators
    ea3d_keys<<<dim3(NTOK / 1024, NB), 256, 0, stream>>>(x, Wk, e16, ws);
    ea3d_msum<<<dim3(NTOK / 8192, 8, NB), 256, 0, stream>>>(x, e16, ws);
    ea3d_finalize<<<1, 256, 0, stream>>>(Wv, bv, Wr, br, ws);
    ea3d_add<<<dim3(32, NB * NCH), 256, 0, stream>>>(x, ws, out);
}